// Round 9
// baseline (293.961 us; speedup 1.0000x reference)
//
#include <hip/hip_runtime.h>
#include <hip/hip_bf16.h>

typedef unsigned short u16;
typedef unsigned int u32;
typedef __bf16 bf16x8 __attribute__((ext_vector_type(8)));
typedef float f32x4 __attribute__((ext_vector_type(4)));
typedef u16 u16x8 __attribute__((ext_vector_type(8)));
typedef u32 u32x2 __attribute__((ext_vector_type(2)));

#define S_LEN 2048
#define DMODEL 512
#define NHEAD 8
#define DHEAD 64
// Q pre-scaled by (1/sqrt(64))*log2(e) so softmax runs in exp2 domain.
#define QSCALE 0.1803368801111204f
#define MASKC 1.4426950409e9f

static __device__ __forceinline__ u16 f2bf(float f) {
    union { float f; unsigned u; } cv; cv.f = f;
    unsigned u = cv.u;
    return (u16)((u + 0x7fffu + ((u >> 16) & 1u)) >> 16);  // RNE
}
static __device__ __forceinline__ u32 pk2bf(float a, float b) {
    union { __hip_bfloat162 h; u32 u; } cv;
    float2 f2; f2.x = a; f2.y = b;
    cv.h = __float22bfloat162_rn(f2);
    return cv.u;
}
static __device__ __forceinline__ bf16x8 ld8(const u16* p) {
    return *(const bf16x8*)p;
}

// ---------------- fused prep: qkv fp32->bf16 cvt | weight transpose->bf16 | mask flags ----
__global__ __launch_bounds__(256) void prep_kernel(
    const float* __restrict__ q, const float* __restrict__ k, const float* __restrict__ v,
    const float* __restrict__ w0, const float* __restrict__ w1,
    const float* __restrict__ w2, const float* __restrict__ w3,
    const float* __restrict__ mask,
    u16* __restrict__ Aqkv, u16* __restrict__ wtall, int* __restrict__ flags) {
    const int p = blockIdx.x;
    const int tid = threadIdx.x;
    __shared__ float t[32][33];
    __shared__ int wred[4];
    if (p < 3072) {
        const int z = p >> 10, px = p & 1023;
        const float* in = (z == 0) ? q : (z == 1) ? k : v;
        u16* o = Aqkv + (long)z * 2097152;
        long i = ((long)px * 256 + tid) * 8;
        f32x4 a = *(const f32x4*)(in + i);
        f32x4 b = *(const f32x4*)(in + i + 4);
        u16x8 r;
#pragma unroll
        for (int j = 0; j < 4; ++j) { r[j] = f2bf(a[j]); r[4 + j] = f2bf(b[j]); }
        *(u16x8*)(o + i) = r;
    } else if (p < 4096) {
        // W (512x512 fp32) -> Wt bf16 (N x K). slot order in wtall: [wo, wq, wk, wv]
        const int p2 = p - 3072;
        const int z = p2 >> 8, rem = p2 & 255, by = rem >> 4, bx = rem & 15;
        const float* in = (z == 0) ? w0 : (z == 1) ? w1 : (z == 2) ? w2 : w3;
        u16* o = wtall + (long)(((z + 1) & 3)) * 262144;
        const int tx = tid & 31, ty = tid >> 5;
#pragma unroll
        for (int i = 0; i < 4; ++i)
            t[ty + 8 * i][tx] = in[(by * 32 + ty + 8 * i) * DMODEL + bx * 32 + tx];
        __syncthreads();
#pragma unroll
        for (int i = 0; i < 4; ++i)
            o[(bx * 32 + ty + 8 * i) * DMODEL + by * 32 + tx] = f2bf(t[tx][ty + 8 * i]);
    } else {
        const int bid = p - 4096;  // 2*32*32
        const int b = bid >> 10, qt = (bid >> 5) & 31, kt = bid & 31;
        const int r = tid >> 2, cs = tid & 3;
        const float* mp = mask + ((long)(b * S_LEN + qt * 64 + r)) * S_LEN + kt * 64 + cs * 16;
        int nz = 0;
#pragma unroll
        for (int j = 0; j < 4; ++j) {
            f32x4 a = *(const f32x4*)(mp + j * 4);
            nz |= (a[0] != 0.f) | (a[1] != 0.f) | (a[2] != 0.f) | (a[3] != 0.f);
        }
        unsigned long long ball = __ballot(nz);
        if ((tid & 63) == 0) wred[tid >> 6] = (ball != 0ull) ? 1 : 0;
        __syncthreads();
        if (tid == 0) flags[bid] = wred[0] | wred[1] | wred[2] | wred[3];
    }
}

// V merged bf16 (B,S,512) -> Vt bf16 (B,H,DH,S)
__global__ void transpose_v_kernel(const u16* __restrict__ V, u16* __restrict__ Vt) {
    int z = blockIdx.z;
    int b = z >> 3, h = z & 7;
    const u16* in = V + (long)b * S_LEN * DMODEL + h * DHEAD;
    u16* out = Vt + (long)z * DHEAD * S_LEN;
    __shared__ u16 t[32][33];
    int tx = threadIdx.x, ty = threadIdx.y;
    int r = blockIdx.y * 32 + ty;  // s
    int c = blockIdx.x * 32 + tx;  // d
    t[ty][tx] = in[(long)r * DMODEL + c];
    __syncthreads();
    int orow = blockIdx.x * 32 + ty;  // d
    int ocol = blockIdx.y * 32 + tx;  // s
    out[(long)orow * S_LEN + ocol] = t[tx][ty];
}

// ---------------- GEMM: C(4096x512) = A(4096x512) @ W + bias; block tile (TM*32) x 64,
// 4 waves (2x2), wave tile (TM*16) x 32.
template <bool F32OUT, int TM>
static __device__ __forceinline__ void gemm_body(const u16* __restrict__ A,
                                                 const u16* __restrict__ Wt,
                                                 const float* __restrict__ bias,
                                                 void* __restrict__ Cp, float oscale) {
    const int lane = threadIdx.x & 63;
    const int wave = threadIdx.x >> 6;
    const int wr = wave >> 1, wc = wave & 1;
    const int m0 = blockIdx.y * (TM * 32) + wr * (TM * 16);
    const int n0 = blockIdx.x * 64 + wc * 32;
    const int cidx = lane & 15;
    const int kg = lane >> 4;

    const u16* aptr[TM];
    const u16* bptr[2];
#pragma unroll
    for (int t = 0; t < TM; ++t)
        aptr[t] = A + (long)(m0 + t * 16 + cidx) * DMODEL + kg * 8;
#pragma unroll
    for (int t = 0; t < 2; ++t)
        bptr[t] = Wt + (long)(n0 + t * 16 + cidx) * DMODEL + kg * 8;

    const f32x4 fz = {0.f, 0.f, 0.f, 0.f};
    f32x4 acc[TM][2];
#pragma unroll
    for (int i = 0; i < TM; ++i)
#pragma unroll
        for (int j = 0; j < 2; ++j) acc[i][j] = fz;

#pragma unroll 4
    for (int k0 = 0; k0 < 512; k0 += 32) {
        bf16x8 a[TM], b[2];
#pragma unroll
        for (int t = 0; t < TM; ++t) a[t] = ld8(aptr[t] + k0);
#pragma unroll
        for (int t = 0; t < 2; ++t) b[t] = ld8(bptr[t] + k0);
#pragma unroll
        for (int i = 0; i < TM; ++i)
#pragma unroll
            for (int j = 0; j < 2; ++j)
                acc[i][j] = __builtin_amdgcn_mfma_f32_16x16x32_bf16(a[i], b[j], acc[i][j], 0, 0, 0);
    }

#pragma unroll
    for (int j = 0; j < 2; ++j) {
        int col = n0 + j * 16 + cidx;
        float bv = bias[col];
#pragma unroll
        for (int i = 0; i < TM; ++i) {
#pragma unroll
            for (int r = 0; r < 4; ++r) {
                int row = m0 + i * 16 + kg * 4 + r;
                float val = (acc[i][j][r] + bv) * oscale;
                if (F32OUT) {
                    ((float*)Cp)[(long)row * DMODEL + col] = val;
                } else {
                    ((u16*)Cp)[(long)row * DMODEL + col] = f2bf(val);
                }
            }
        }
    }
}

__global__ __launch_bounds__(256) void qkv_gemm_kernel(
    const u16* __restrict__ Aqkv,
    const u16* __restrict__ wtall,
    const float* __restrict__ bq, const float* __restrict__ bk, const float* __restrict__ bv,
    u16* __restrict__ Q, u16* __restrict__ K, u16* __restrict__ V) {
    const u16* A = Aqkv + (long)blockIdx.z * 2097152;
    const u16* W = wtall + (long)(blockIdx.z + 1) * 262144;  // [wo, wq, wk, wv]
    const float* b;
    u16* C;
    float sc = 1.f;
    if (blockIdx.z == 0) { b = bq; C = Q; sc = QSCALE; }
    else if (blockIdx.z == 1) { b = bk; C = K; }
    else { b = bv; C = V; }
    gemm_body<false, 4>(A, W, b, C, sc);
}

__global__ __launch_bounds__(256) void out_gemm_kernel(const u16* __restrict__ A,
                                                       const u16* __restrict__ Wt,
                                                       const float* __restrict__ bias,
                                                       float* __restrict__ C) {
    gemm_body<true, 2>(A, Wt, bias, C, 1.f);
}

// ---------------- flash attention: wave-owns-keys, no-max softmax, single-pass --------
// grid: (S/32, B*H), block 256 (4 waves). Block owns 32 q-rows and the FULL key range;
// per iter the block covers 256 keys, wave w the slice [it*256 + w*64, +64).
// K/V stream global->registers (no staging, no loop barriers). LDS only for the per-wave
// P^T transform and the final cross-wave O/l reduction. m=0 softmax (exp2 domain).
// Writes normalized output directly to Ab (no split/combine).
// Sized for occupancy: ~118 VGPR (launch_bounds caps 128 -> 4 waves/SIMD), LDS 16.9 KB ->
// exactly 4 blocks/CU -> whole 1024-block grid co-resident, 8 deep K-iterations per wave.
// NOTE: no runtime indices into register arrays (r7: dynamic index => 227 MB scratch spill).
__global__ __launch_bounds__(256, 4) void attn_kernel(const u16* __restrict__ Q,
                                                      const u16* __restrict__ K,
                                                      const u16* __restrict__ Vt,
                                                      const float* __restrict__ mask,
                                                      const int* __restrict__ flags,
                                                      u16* __restrict__ Ab) {
    const int tid = threadIdx.x;
    const int lane = tid & 63;
    const int wave = tid >> 6;
    const int cidx = lane & 15;
    const int kg = lane >> 4;
    const int bh = blockIdx.y;
    const int b = bh >> 3, h = bh & 7;
    const int q0blk = blockIdx.x * 32;

    __shared__ u16 p_lds[4][32 * 64];  // per-wave P^T [q-local][key-local], swizzled; 16 KB
    __shared__ float lds_l[4][32];
    u16* pw = p_lds[wave];

    // Q fragments for the block's 2 q-tiles (B-operand of K.Q^T)
    const u16* qbase = Q + ((long)(b * S_LEN + q0blk + cidx)) * DMODEL + h * DHEAD + kg * 8;
    bf16x8 qf[2][2];
#pragma unroll
    for (int nt = 0; nt < 2; ++nt) {
        qf[nt][0] = ld8(qbase + (long)(nt * 16) * DMODEL);
        qf[nt][1] = ld8(qbase + (long)(nt * 16) * DMODEL + 32);
    }

    const f32x4 fz = {0.f, 0.f, 0.f, 0.f};
    f32x4 acc[4][2];  // O^T partial: acc[dht][qt]; lane holds O[dh=dht*16+kg*4+r][q=qt*16+cidx]
#pragma unroll
    for (int i = 0; i < 4; ++i)
#pragma unroll
        for (int j = 0; j < 2; ++j) acc[i][j] = fz;
    float lrow[2] = {0.f, 0.f};  // per-lane partial denom per q-tile

    const u16* kKb = K + ((long)(b * S_LEN + cidx)) * DMODEL + h * DHEAD + kg * 8;
    const u16* vVb = Vt + ((long)(bh * DHEAD + cidx)) * S_LEN + kg * 8;
    const int* flagrow = flags + b * 1024 + (blockIdx.x >> 1) * 32;

#pragma unroll 2
    for (int it = 0; it < S_LEN / 256; ++it) {
        const int koff = it * 256 + wave * 64;  // this wave's 64-key slice
        const int flg = flagrow[it * 4 + wave];

        // V^T fragments for this key slice (A-operand of V^T.P^T)
        bf16x8 vf[4][2];
#pragma unroll
        for (int dht = 0; dht < 4; ++dht) {
            const u16* vp = vVb + (long)(dht * 16) * S_LEN + koff;
            vf[dht][0] = ld8(vp);
            vf[dht][1] = ld8(vp + 32);
        }

        // ---- S^T = K.Q^T per 16-key tile; exp2; pack P^T into per-wave LDS ----
#pragma unroll
        for (int ct = 0; ct < 4; ++ct) {
            const u16* kp = kKb + (long)(koff + ct * 16) * DMODEL;
            bf16x8 kf0 = ld8(kp);
            bf16x8 kf1 = ld8(kp + 32);
            f32x4 sacc[2];
#pragma unroll
            for (int nt = 0; nt < 2; ++nt) {
                sacc[nt] = __builtin_amdgcn_mfma_f32_16x16x32_bf16(kf0, qf[nt][0], fz, 0, 0, 0);
                sacc[nt] = __builtin_amdgcn_mfma_f32_16x16x32_bf16(kf1, qf[nt][1], sacc[nt], 0, 0, 0);
            }
            if (flg) {  // rare slow path; exact fp32 mask from global
#pragma unroll
                for (int nt = 0; nt < 2; ++nt) {
                    const float* mb = mask + ((long)(b * S_LEN + q0blk + nt * 16 + cidx)) * S_LEN
                                      + koff + ct * 16 + kg * 4;
                    f32x4 mv = *(const f32x4*)mb;
#pragma unroll
                    for (int r = 0; r < 4; ++r) sacc[nt][r] -= MASKC * mv[r];
                }
            }
#pragma unroll
            for (int nt = 0; nt < 2; ++nt) {
                float p0 = exp2f(sacc[nt][0]);
                float p1 = exp2f(sacc[nt][1]);
                float p2 = exp2f(sacc[nt][2]);
                float p3 = exp2f(sacc[nt][3]);
                lrow[nt] += (p0 + p1) + (p2 + p3);
                u32x2 d;
                d[0] = pk2bf(p0, p1);
                d[1] = pk2bf(p2, p3);
                int q = nt * 16 + cidx;  // P^T row; keys ct*16+kg*4.. contiguous
                int blk = 2 * ct + (kg >> 1);
                *(u32x2*)&pw[q * 64 + ((blk ^ (q & 7)) << 3) + (kg & 1) * 4] = d;
            }
        }
        // ---- read P^T B-fragments (wave-local; DS pipe in-order, no barrier) ----
#pragma unroll
        for (int qt = 0; qt < 2; ++qt) {
            int q = qt * 16 + cidx;
            bf16x8 pf0 = ld8(&pw[q * 64 + ((kg ^ (q & 7)) << 3)]);
            bf16x8 pf1 = ld8(&pw[q * 64 + (((4 ^ kg) ^ (q & 7)) << 3)]);
#pragma unroll
            for (int dht = 0; dht < 4; ++dht) {
                acc[dht][qt] = __builtin_amdgcn_mfma_f32_16x16x32_bf16(vf[dht][0], pf0, acc[dht][qt], 0, 0, 0);
                acc[dht][qt] = __builtin_amdgcn_mfma_f32_16x16x32_bf16(vf[dht][1], pf1, acc[dht][qt], 0, 0, 0);
            }
        }
    }

    // ---- epilogue: cross-wave reduction of O and l, normalize, write Ab ----
#pragma unroll
    for (int nt = 0; nt < 2; ++nt) {
        lrow[nt] += __shfl_xor(lrow[nt], 16);
        lrow[nt] += __shfl_xor(lrow[nt], 32);
    }
    if (kg == 0) {
#pragma unroll
        for (int nt = 0; nt < 2; ++nt) lds_l[wave][nt * 16 + cidx] = lrow[nt];
    }
    // red[w2][dj][qt][lane][4] floats = 16 KB, aliases p_lds
    float* red = (float*)p_lds;
    const int djw = wave >> 1, qtw = wave & 1;  // this wave's output assignment
    f32x4 ofin[2];
#pragma unroll
    for (int h2 = 0; h2 < 2; ++h2) {
        __syncthreads();  // P reads done (h2=0) / pass-0 reads done (h2=1); lds_l visible
#pragma unroll
        for (int dj = 0; dj < 2; ++dj) {
#pragma unroll
            for (int qt = 0; qt < 2; ++qt)
                *(f32x4*)&red[wave * 1024 + (dj * 2 + qt) * 256 + lane * 4] = acc[h2 * 2 + dj][qt];
        }
        __syncthreads();
        f32x4 s = *(const f32x4*)&red[0 * 1024 + (djw * 2 + qtw) * 256 + lane * 4];
#pragma unroll
        for (int w2 = 1; w2 < 4; ++w2)
            s += *(const f32x4*)&red[w2 * 1024 + (djw * 2 + qtw) * 256 + lane * 4];
        ofin[h2] = s;
    }
    float L = lds_l[0][qtw * 16 + cidx] + lds_l[1][qtw * 16 + cidx] +
              lds_l[2][qtw * 16 + cidx] + lds_l[3][qtw * 16 + cidx];
    float invL = 1.f / L;
    const long obase = ((long)(b * S_LEN + q0blk + qtw * 16 + cidx)) * DMODEL + h * DHEAD;
#pragma unroll
    for (int h2 = 0; h2 < 2; ++h2) {
        int dht = h2 * 2 + djw;
        u32x2 d;
        d[0] = pk2bf(ofin[h2][0] * invL, ofin[h2][1] * invL);
        d[1] = pk2bf(ofin[h2][2] * invL, ofin[h2][3] * invL);
        *(u32x2*)(Ab + obase + dht * 16 + kg * 4) = d;
    }
}

extern "C" void kernel_launch(void* const* d_in, const int* in_sizes, int n_in,
                              void* d_out, int out_size, void* d_ws, size_t ws_size,
                              hipStream_t stream) {
    const float* q_in = (const float*)d_in[0];
    const float* k_in = (const float*)d_in[1];
    const float* v_in = (const float*)d_in[2];
    const float* mask = (const float*)d_in[3];
    const float* wq = (const float*)d_in[4];
    const float* bq = (const float*)d_in[5];
    const float* wk = (const float*)d_in[6];
    const float* bk = (const float*)d_in[7];
    const float* wv = (const float*)d_in[8];
    const float* bv = (const float*)d_in[9];
    const float* wo = (const float*)d_in[10];
    const float* bo = (const float*)d_in[11];

    // ws layout (u16 units)
    u16* ws = (u16*)d_ws;
    u16* Qb = ws;                       // 2.1M  projected Q (pre-scaled QSCALE)
    u16* Kb = Qb + 2097152;             // 2.1M
    u16* Vt = Kb + 2097152;             // 2.1M  V transposed (B,H,DH,S)
    u16* wtall = Vt + 2097152;          // 4 x 262144: [wo, wq, wk, wv]
    u16* Sreg = wtall + 4 * 262144;     // 3 x 2.1M: Aq,Ak,Av  (dead after qkv_gemm)
    u16* Vb = Sreg + 3 * 2097152;       // 2.1M  merged V    (dead after transpose_v)
    u16* Ab = Vb + 2097152;             // 2.1M  attention output (merged heads)
    int* mflags = (int*)(Ab + 2097152); // 2048 ints

    prep_kernel<<<6144, 256, 0, stream>>>(q_in, k_in, v_in, wq, wk, wv, wo, mask,
                                          Sreg, wtall, mflags);
    qkv_gemm_kernel<<<dim3(8, 32, 3), 256, 0, stream>>>(Sreg, wtall, bq, bk, bv, Qb, Kb, Vb);
    transpose_v_kernel<<<dim3(2, 64, 16), dim3(32, 32), 0, stream>>>(Vb, Vt);
    attn_kernel<<<dim3(64, 16), 256, 0, stream>>>(Qb, Kb, Vt, mask, mflags, Ab);
    out_gemm_kernel<<<dim3(8, 64), 256, 0, stream>>>(Ab, wtall, bo, (float*)d_out);
}

// Round 10
// 237.247 us; speedup vs baseline: 1.2390x; 1.2390x over previous
//
#include <hip/hip_runtime.h>
#include <hip/hip_bf16.h>

typedef unsigned short u16;
typedef unsigned int u32;
typedef __bf16 bf16x8 __attribute__((ext_vector_type(8)));
typedef float f32x4 __attribute__((ext_vector_type(4)));
typedef u16 u16x8 __attribute__((ext_vector_type(8)));
typedef u32 u32x2 __attribute__((ext_vector_type(2)));

#define S_LEN 2048
#define DMODEL 512
#define NHEAD 8
#define DHEAD 64
// Q pre-scaled by (1/sqrt(64))*log2(e) so softmax runs in exp2 domain.
#define QSCALE 0.1803368801111204f
#define MASKC 1.4426950409e9f

static __device__ __forceinline__ u16 f2bf(float f) {
    union { float f; unsigned u; } cv; cv.f = f;
    unsigned u = cv.u;
    return (u16)((u + 0x7fffu + ((u >> 16) & 1u)) >> 16);  // RNE
}
static __device__ __forceinline__ u32 pk2bf(float a, float b) {
    union { __hip_bfloat162 h; u32 u; } cv;
    float2 f2; f2.x = a; f2.y = b;
    cv.h = __float22bfloat162_rn(f2);
    return cv.u;
}
static __device__ __forceinline__ bf16x8 ld8(const u16* p) {
    return *(const bf16x8*)p;
}

// ---------------- fused prep: qkv fp32->bf16 cvt | weight transpose->bf16 | mask flags ----
__global__ __launch_bounds__(256) void prep_kernel(
    const float* __restrict__ q, const float* __restrict__ k, const float* __restrict__ v,
    const float* __restrict__ w0, const float* __restrict__ w1,
    const float* __restrict__ w2, const float* __restrict__ w3,
    const float* __restrict__ mask,
    u16* __restrict__ Aqkv, u16* __restrict__ wtall, int* __restrict__ flags) {
    const int p = blockIdx.x;
    const int tid = threadIdx.x;
    __shared__ float t[32][33];
    __shared__ int wred[4];
    if (p < 3072) {
        const int z = p >> 10, px = p & 1023;
        const float* in = (z == 0) ? q : (z == 1) ? k : v;
        u16* o = Aqkv + (long)z * 2097152;
        long i = ((long)px * 256 + tid) * 8;
        f32x4 a = *(const f32x4*)(in + i);
        f32x4 b = *(const f32x4*)(in + i + 4);
        u16x8 r;
#pragma unroll
        for (int j = 0; j < 4; ++j) { r[j] = f2bf(a[j]); r[4 + j] = f2bf(b[j]); }
        *(u16x8*)(o + i) = r;
    } else if (p < 4096) {
        // W (512x512 fp32) -> Wt bf16 (N x K). slot order in wtall: [wo, wq, wk, wv]
        const int p2 = p - 3072;
        const int z = p2 >> 8, rem = p2 & 255, by = rem >> 4, bx = rem & 15;
        const float* in = (z == 0) ? w0 : (z == 1) ? w1 : (z == 2) ? w2 : w3;
        u16* o = wtall + (long)(((z + 1) & 3)) * 262144;
        const int tx = tid & 31, ty = tid >> 5;
#pragma unroll
        for (int i = 0; i < 4; ++i)
            t[ty + 8 * i][tx] = in[(by * 32 + ty + 8 * i) * DMODEL + bx * 32 + tx];
        __syncthreads();
#pragma unroll
        for (int i = 0; i < 4; ++i)
            o[(bx * 32 + ty + 8 * i) * DMODEL + by * 32 + tx] = f2bf(t[tx][ty + 8 * i]);
    } else {
        const int bid = p - 4096;  // 2*32*32
        const int b = bid >> 10, qt = (bid >> 5) & 31, kt = bid & 31;
        const int r = tid >> 2, cs = tid & 3;
        const float* mp = mask + ((long)(b * S_LEN + qt * 64 + r)) * S_LEN + kt * 64 + cs * 16;
        int nz = 0;
#pragma unroll
        for (int j = 0; j < 4; ++j) {
            f32x4 a = *(const f32x4*)(mp + j * 4);
            nz |= (a[0] != 0.f) | (a[1] != 0.f) | (a[2] != 0.f) | (a[3] != 0.f);
        }
        unsigned long long ball = __ballot(nz);
        if ((tid & 63) == 0) wred[tid >> 6] = (ball != 0ull) ? 1 : 0;
        __syncthreads();
        if (tid == 0) flags[bid] = wred[0] | wred[1] | wred[2] | wred[3];
    }
}

// V merged bf16 (B,S,512) -> Vt bf16 (B,H,DH,S)
__global__ void transpose_v_kernel(const u16* __restrict__ V, u16* __restrict__ Vt) {
    int z = blockIdx.z;
    int b = z >> 3, h = z & 7;
    const u16* in = V + (long)b * S_LEN * DMODEL + h * DHEAD;
    u16* out = Vt + (long)z * DHEAD * S_LEN;
    __shared__ u16 t[32][33];
    int tx = threadIdx.x, ty = threadIdx.y;
    int r = blockIdx.y * 32 + ty;  // s
    int c = blockIdx.x * 32 + tx;  // d
    t[ty][tx] = in[(long)r * DMODEL + c];
    __syncthreads();
    int orow = blockIdx.x * 32 + ty;  // d
    int ocol = blockIdx.y * 32 + tx;  // s
    out[(long)orow * S_LEN + ocol] = t[tx][ty];
}

// ---------------- GEMM: C(4096x512) = A(4096x512) @ W + bias; block tile (TM*32) x 64,
// 4 waves (2x2), wave tile (TM*16) x 32.
template <bool F32OUT, int TM>
static __device__ __forceinline__ void gemm_body(const u16* __restrict__ A,
                                                 const u16* __restrict__ Wt,
                                                 const float* __restrict__ bias,
                                                 void* __restrict__ Cp, float oscale) {
    const int lane = threadIdx.x & 63;
    const int wave = threadIdx.x >> 6;
    const int wr = wave >> 1, wc = wave & 1;
    const int m0 = blockIdx.y * (TM * 32) + wr * (TM * 16);
    const int n0 = blockIdx.x * 64 + wc * 32;
    const int cidx = lane & 15;
    const int kg = lane >> 4;

    const u16* aptr[TM];
    const u16* bptr[2];
#pragma unroll
    for (int t = 0; t < TM; ++t)
        aptr[t] = A + (long)(m0 + t * 16 + cidx) * DMODEL + kg * 8;
#pragma unroll
    for (int t = 0; t < 2; ++t)
        bptr[t] = Wt + (long)(n0 + t * 16 + cidx) * DMODEL + kg * 8;

    const f32x4 fz = {0.f, 0.f, 0.f, 0.f};
    f32x4 acc[TM][2];
#pragma unroll
    for (int i = 0; i < TM; ++i)
#pragma unroll
        for (int j = 0; j < 2; ++j) acc[i][j] = fz;

#pragma unroll 4
    for (int k0 = 0; k0 < 512; k0 += 32) {
        bf16x8 a[TM], b[2];
#pragma unroll
        for (int t = 0; t < TM; ++t) a[t] = ld8(aptr[t] + k0);
#pragma unroll
        for (int t = 0; t < 2; ++t) b[t] = ld8(bptr[t] + k0);
#pragma unroll
        for (int i = 0; i < TM; ++i)
#pragma unroll
            for (int j = 0; j < 2; ++j)
                acc[i][j] = __builtin_amdgcn_mfma_f32_16x16x32_bf16(a[i], b[j], acc[i][j], 0, 0, 0);
    }

#pragma unroll
    for (int j = 0; j < 2; ++j) {
        int col = n0 + j * 16 + cidx;
        float bv = bias[col];
#pragma unroll
        for (int i = 0; i < TM; ++i) {
#pragma unroll
            for (int r = 0; r < 4; ++r) {
                int row = m0 + i * 16 + kg * 4 + r;
                float val = (acc[i][j][r] + bv) * oscale;
                if (F32OUT) {
                    ((float*)Cp)[(long)row * DMODEL + col] = val;
                } else {
                    ((u16*)Cp)[(long)row * DMODEL + col] = f2bf(val);
                }
            }
        }
    }
}

__global__ __launch_bounds__(256) void qkv_gemm_kernel(
    const u16* __restrict__ Aqkv,
    const u16* __restrict__ wtall,
    const float* __restrict__ bq, const float* __restrict__ bk, const float* __restrict__ bv,
    u16* __restrict__ Q, u16* __restrict__ K, u16* __restrict__ V) {
    const u16* A = Aqkv + (long)blockIdx.z * 2097152;
    const u16* W = wtall + (long)(blockIdx.z + 1) * 262144;  // [wo, wq, wk, wv]
    const float* b;
    u16* C;
    float sc = 1.f;
    if (blockIdx.z == 0) { b = bq; C = Q; sc = QSCALE; }
    else if (blockIdx.z == 1) { b = bk; C = K; }
    else { b = bv; C = V; }
    gemm_body<false, 4>(A, W, b, C, sc);
}

__global__ __launch_bounds__(256) void out_gemm_kernel(const u16* __restrict__ A,
                                                       const u16* __restrict__ Wt,
                                                       const float* __restrict__ bias,
                                                       float* __restrict__ C) {
    gemm_body<true, 2>(A, Wt, bias, C, 1.f);
}

// ---------------- flash attention: wave-owns-keys, no-max softmax, single-pass --------
// grid: (S/32, B*H), block 256 (4 waves). Block owns 32 q-rows and the FULL key range;
// per iter the block covers 256 keys, wave w the slice [it*256 + w*64, +64).
// K/V stream global->registers (no staging, no loop barriers). LDS only for the per-wave
// P^T transform and the final cross-wave O/l reduction. m=0 softmax (exp2 domain).
// Writes normalized output directly to Ab (no split/combine).
// NOTE 1: no runtime indices into register arrays (r7: dynamic index => 227 MB scratch).
// NOTE 2: NO min-waves arg in launch_bounds — r9's (256,4) capped VGPR at 64 and spilled
//         500 MB/dispatch to scratch. Allocator must run free here (r8: 148 VGPR, 0 spill).
__global__ __launch_bounds__(256) void attn_kernel(const u16* __restrict__ Q,
                                                   const u16* __restrict__ K,
                                                   const u16* __restrict__ Vt,
                                                   const float* __restrict__ mask,
                                                   const int* __restrict__ flags,
                                                   u16* __restrict__ Ab) {
    const int tid = threadIdx.x;
    const int lane = tid & 63;
    const int wave = tid >> 6;
    const int cidx = lane & 15;
    const int kg = lane >> 4;
    const int bh = blockIdx.y;
    const int b = bh >> 3, h = bh & 7;
    const int q0blk = blockIdx.x * 32;

    __shared__ u16 p_lds[4][32 * 64];  // per-wave P^T [q-local][key-local], swizzled; 16 KB
    __shared__ float lds_l[4][32];
    u16* pw = p_lds[wave];

    // Q fragments for the block's 2 q-tiles (B-operand of K.Q^T)
    const u16* qbase = Q + ((long)(b * S_LEN + q0blk + cidx)) * DMODEL + h * DHEAD + kg * 8;
    bf16x8 qf[2][2];
#pragma unroll
    for (int nt = 0; nt < 2; ++nt) {
        qf[nt][0] = ld8(qbase + (long)(nt * 16) * DMODEL);
        qf[nt][1] = ld8(qbase + (long)(nt * 16) * DMODEL + 32);
    }

    const f32x4 fz = {0.f, 0.f, 0.f, 0.f};
    f32x4 acc[4][2];  // O^T partial: acc[dht][qt]; lane holds O[dh=dht*16+kg*4+r][q=qt*16+cidx]
#pragma unroll
    for (int i = 0; i < 4; ++i)
#pragma unroll
        for (int j = 0; j < 2; ++j) acc[i][j] = fz;
    float lrow[2] = {0.f, 0.f};  // per-lane partial denom per q-tile

    const u16* kKb = K + ((long)(b * S_LEN + cidx)) * DMODEL + h * DHEAD + kg * 8;
    const u16* vVb = Vt + ((long)(bh * DHEAD + cidx)) * S_LEN + kg * 8;
    const int* flagrow = flags + b * 1024 + (blockIdx.x >> 1) * 32;

#pragma unroll 2
    for (int it = 0; it < S_LEN / 256; ++it) {
        const int koff = it * 256 + wave * 64;  // this wave's 64-key slice
        const int flg = flagrow[it * 4 + wave];

        // V^T fragments for this key slice (A-operand of V^T.P^T)
        bf16x8 vf[4][2];
#pragma unroll
        for (int dht = 0; dht < 4; ++dht) {
            const u16* vp = vVb + (long)(dht * 16) * S_LEN + koff;
            vf[dht][0] = ld8(vp);
            vf[dht][1] = ld8(vp + 32);
        }

        // ---- S^T = K.Q^T per 16-key tile; exp2; pack P^T into per-wave LDS ----
#pragma unroll
        for (int ct = 0; ct < 4; ++ct) {
            const u16* kp = kKb + (long)(koff + ct * 16) * DMODEL;
            bf16x8 kf0 = ld8(kp);
            bf16x8 kf1 = ld8(kp + 32);
            f32x4 sacc[2];
#pragma unroll
            for (int nt = 0; nt < 2; ++nt) {
                sacc[nt] = __builtin_amdgcn_mfma_f32_16x16x32_bf16(kf0, qf[nt][0], fz, 0, 0, 0);
                sacc[nt] = __builtin_amdgcn_mfma_f32_16x16x32_bf16(kf1, qf[nt][1], sacc[nt], 0, 0, 0);
            }
            if (flg) {  // rare slow path; exact fp32 mask from global
#pragma unroll
                for (int nt = 0; nt < 2; ++nt) {
                    const float* mb = mask + ((long)(b * S_LEN + q0blk + nt * 16 + cidx)) * S_LEN
                                      + koff + ct * 16 + kg * 4;
                    f32x4 mv = *(const f32x4*)mb;
#pragma unroll
                    for (int r = 0; r < 4; ++r) sacc[nt][r] -= MASKC * mv[r];
                }
            }
#pragma unroll
            for (int nt = 0; nt < 2; ++nt) {
                float p0 = exp2f(sacc[nt][0]);
                float p1 = exp2f(sacc[nt][1]);
                float p2 = exp2f(sacc[nt][2]);
                float p3 = exp2f(sacc[nt][3]);
                lrow[nt] += (p0 + p1) + (p2 + p3);
                u32x2 d;
                d[0] = pk2bf(p0, p1);
                d[1] = pk2bf(p2, p3);
                int q = nt * 16 + cidx;  // P^T row; keys ct*16+kg*4.. contiguous
                int blk = 2 * ct + (kg >> 1);
                *(u32x2*)&pw[q * 64 + ((blk ^ (q & 7)) << 3) + (kg & 1) * 4] = d;
            }
        }
        // ---- read P^T B-fragments (wave-local; DS pipe in-order, no barrier) ----
#pragma unroll
        for (int qt = 0; qt < 2; ++qt) {
            int q = qt * 16 + cidx;
            bf16x8 pf0 = ld8(&pw[q * 64 + ((kg ^ (q & 7)) << 3)]);
            bf16x8 pf1 = ld8(&pw[q * 64 + (((4 ^ kg) ^ (q & 7)) << 3)]);
#pragma unroll
            for (int dht = 0; dht < 4; ++dht) {
                acc[dht][qt] = __builtin_amdgcn_mfma_f32_16x16x32_bf16(vf[dht][0], pf0, acc[dht][qt], 0, 0, 0);
                acc[dht][qt] = __builtin_amdgcn_mfma_f32_16x16x32_bf16(vf[dht][1], pf1, acc[dht][qt], 0, 0, 0);
            }
        }
    }

    // ---- epilogue: cross-wave reduction of O and l, normalize, write Ab ----
#pragma unroll
    for (int nt = 0; nt < 2; ++nt) {
        lrow[nt] += __shfl_xor(lrow[nt], 16);
        lrow[nt] += __shfl_xor(lrow[nt], 32);
    }
    if (kg == 0) {
#pragma unroll
        for (int nt = 0; nt < 2; ++nt) lds_l[wave][nt * 16 + cidx] = lrow[nt];
    }
    // red[w2][dj][qt][lane][4] floats = 16 KB, aliases p_lds
    float* red = (float*)p_lds;
    const int djw = wave >> 1, qtw = wave & 1;  // this wave's output assignment
    f32x4 ofin[2];
#pragma unroll
    for (int h2 = 0; h2 < 2; ++h2) {
        __syncthreads();  // P reads done (h2=0) / pass-0 reads done (h2=1); lds_l visible
#pragma unroll
        for (int dj = 0; dj < 2; ++dj) {
#pragma unroll
            for (int qt = 0; qt < 2; ++qt)
                *(f32x4*)&red[wave * 1024 + (dj * 2 + qt) * 256 + lane * 4] = acc[h2 * 2 + dj][qt];
        }
        __syncthreads();
        f32x4 s = *(const f32x4*)&red[0 * 1024 + (djw * 2 + qtw) * 256 + lane * 4];
#pragma unroll
        for (int w2 = 1; w2 < 4; ++w2)
            s += *(const f32x4*)&red[w2 * 1024 + (djw * 2 + qtw) * 256 + lane * 4];
        ofin[h2] = s;
    }
    float L = lds_l[0][qtw * 16 + cidx] + lds_l[1][qtw * 16 + cidx] +
              lds_l[2][qtw * 16 + cidx] + lds_l[3][qtw * 16 + cidx];
    float invL = 1.f / L;
    const long obase = ((long)(b * S_LEN + q0blk + qtw * 16 + cidx)) * DMODEL + h * DHEAD;
#pragma unroll
    for (int h2 = 0; h2 < 2; ++h2) {
        int dht = h2 * 2 + djw;
        u32x2 d;
        d[0] = pk2bf(ofin[h2][0] * invL, ofin[h2][1] * invL);
        d[1] = pk2bf(ofin[h2][2] * invL, ofin[h2][3] * invL);
        *(u32x2*)(Ab + obase + dht * 16 + kg * 4) = d;
    }
}

extern "C" void kernel_launch(void* const* d_in, const int* in_sizes, int n_in,
                              void* d_out, int out_size, void* d_ws, size_t ws_size,
                              hipStream_t stream) {
    const float* q_in = (const float*)d_in[0];
    const float* k_in = (const float*)d_in[1];
    const float* v_in = (const float*)d_in[2];
    const float* mask = (const float*)d_in[3];
    const float* wq = (const float*)d_in[4];
    const float* bq = (const float*)d_in[5];
    const float* wk = (const float*)d_in[6];
    const float* bk = (const float*)d_in[7];
    const float* wv = (const float*)d_in[8];
    const float* bv = (const float*)d_in[9];
    const float* wo = (const float*)d_in[10];
    const float* bo = (const float*)d_in[11];

    // ws layout (u16 units)
    u16* ws = (u16*)d_ws;
    u16* Qb = ws;                       // 2.1M  projected Q (pre-scaled QSCALE)
    u16* Kb = Qb + 2097152;             // 2.1M
    u16* Vt = Kb + 2097152;             // 2.1M  V transposed (B,H,DH,S)
    u16* wtall = Vt + 2097152;          // 4 x 262144: [wo, wq, wk, wv]
    u16* Sreg = wtall + 4 * 262144;     // 3 x 2.1M: Aq,Ak,Av  (dead after qkv_gemm)
    u16* Vb = Sreg + 3 * 2097152;       // 2.1M  merged V    (dead after transpose_v)
    u16* Ab = Vb + 2097152;             // 2.1M  attention output (merged heads)
    int* mflags = (int*)(Ab + 2097152); // 2048 ints

    prep_kernel<<<6144, 256, 0, stream>>>(q_in, k_in, v_in, wq, wk, wv, wo, mask,
                                          Sreg, wtall, mflags);
    qkv_gemm_kernel<<<dim3(8, 32, 3), 256, 0, stream>>>(Sreg, wtall, bq, bk, bv, Qb, Kb, Vb);
    transpose_v_kernel<<<dim3(2, 64, 16), dim3(32, 32), 0, stream>>>(Vb, Vt);
    attn_kernel<<<dim3(64, 16), 256, 0, stream>>>(Qb, Kb, Vt, mask, mflags, Ab);
    out_gemm_kernel<<<dim3(8, 64), 256, 0, stream>>>(Ab, wtall, bo, (float*)d_out);
}